// Round 2
// baseline (40.644 us; speedup 1.0000x reference)
//
#include <hip/hip_runtime.h>
#include <math.h>

#define SR_I 16000
#define FRAMES 500
#define UP 64
#define AUDIO (FRAMES * UP)
#define POLY 8
#define HARM 64
#define NYQ 8000.0f

__device__ __forceinline__ float readlane_f(float v, int lane) {
    return __uint_as_float(__builtin_amdgcn_readlane(__float_as_uint(v), lane));
}

// -------------------------------------------------------------------------
// Kernel 1: per (b,p) row, exclusive f64 prefix of per-frame sums of
// upsample(f0)/SR.  Frame-sum closed form (scale=64, align_corners=False):
//   interior t:  8*x[t-1] + 48*x[t] + 8*x[t+1]
//   t=0: 56*x[0]+8*x[1];  t=499: 8*x[498]+56*x[499]
// -------------------------------------------------------------------------
__global__ __launch_bounds__(64) void k_prefix(const float* __restrict__ f0,
                                               double* __restrict__ P) {
    const int bp = blockIdx.x;      // 0..15
    const int lane = threadIdx.x;   // 0..63
    const float* x = f0 + bp * FRAMES;
    double* Pp = P + bp * FRAMES;

    double carry = 0.0;
    for (int ch = 0; ch < 8; ++ch) {
        int t = ch * 64 + lane;
        double F = 0.0;
        if (t < FRAMES) {
            double xm = (double)x[t > 0 ? t - 1 : 0];
            double xc = (double)x[t];
            double xp = (double)x[t < FRAMES - 1 ? t + 1 : FRAMES - 1];
            double wa = 8.0, wb = 48.0, wc = 8.0;
            if (t == 0)          { wa = 0.0; wb = 56.0; wc = 8.0; }
            if (t == FRAMES - 1) { wa = 8.0; wb = 56.0; wc = 0.0; }
            F = (wa * xm + wb * xc + wc * xp) * (1.0 / (double)SR_I);
        }
        double s = F;
        #pragma unroll
        for (int off = 1; off < 64; off <<= 1) {
            double o = __shfl_up(s, off, 64);
            if (lane >= off) s += o;
        }
        if (t < FRAMES) Pp[t] = carry + (s - F);   // exclusive prefix
        carry += __shfl(s, 63, 64);
    }
}

// -------------------------------------------------------------------------
// Kernel 2: one block per (b, frame t); 4 waves; wave w handles poly voices
// {2w, 2w+1}.  Lane k owns output sample j = t*64 + k.
// Inner harmonic loop is memory-free: lane k pre-holds c[k, t-1/t/t+1] and
// rp[k]; harmonic n's values are fetched via v_readlane (uniform broadcast).
// -------------------------------------------------------------------------
__global__ __launch_bounds__(256) void k_main(const float* __restrict__ f0,
                                              const float* __restrict__ cc,
                                              const float* __restrict__ vv,
                                              const float* __restrict__ rp,
                                              const double* __restrict__ P,
                                              float* __restrict__ out) {
    const int blk = blockIdx.x;           // 0 .. 2*FRAMES-1
    const int b = blk / FRAMES;
    const int t = blk - b * FRAMES;
    const int tid = threadIdx.x;
    const int wave = tid >> 6;
    const int k = tid & 63;

    // linear-interp coords for sample j = t*64 + k (exact in f32)
    float src = (float)t + ((float)k - 31.5f) * (1.0f / 64.0f);
    src = fmaxf(src, 0.0f);
    const int i0 = (int)src;
    const int i1 = min(i0 + 1, FRAMES - 1);
    const float w = src - (float)i0;
    const float w1 = 1.0f - w;

    const int tm = max(t - 1, 0);
    const int tp = min(t + 1, FRAMES - 1);
    const bool lowhalf = (k < 32);

    float acc = 0.0f;

    for (int pi = 0; pi < 2; ++pi) {
        const int p = wave * 2 + pi;
        const int bpi = b * POLY + p;
        const float* f0p = f0 + bpi * FRAMES;
        const float* vp  = vv + bpi * FRAMES;
        const float* cp  = cc + (size_t)bpi * HARM * FRAMES;

        // lane k holds harmonic k's data for the 3 frames + its random phase
        const float chm = cp[k * FRAMES + tm];
        const float chc = cp[k * FRAMES + t];
        const float chp = cp[k * FRAMES + tp];
        const float rpl = rp[bpi * HARM + k];

        const float f00 = f0p[i0];
        const float f01 = f0p[i1];
        const float vup04 = 0.04f * (w1 * vp[i0] + w * vp[i1]);

        // per-sample phase increment (f64) + 64-lane inclusive scan
        double s = ((double)w1 * (double)f00 + (double)w * (double)f01)
                   * (1.0 / (double)SR_I);
        #pragma unroll
        for (int off = 1; off < 64; off <<= 1) {
            double o = __shfl_up(s, off, 64);
            if (k >= off) s += o;
        }
        const double Phi = P[bpi * FRAMES + t] + s;

        // wave-uniform harmonic cap (all lanes masked beyond hmax)
        float fmn = fminf(f00, f01);
        #pragma unroll
        for (int off = 32; off; off >>= 1)
            fmn = fminf(fmn, __shfl_xor(fmn, off, 64));
        const int hmax = min(HARM, (int)(NYQ / fmn));

        for (int n = 1; n <= hmax; ++n) {
            const float cA = readlane_f(chm, n - 1);
            const float cB = readlane_f(chc, n - 1);
            const float cC = readlane_f(chp, n - 1);
            const float rpn = readlane_f(rpl, n - 1);

            float c0 = lowhalf ? cA : cB;      // frame i0 value
            float c1 = lowhalf ? cB : cC;      // frame i1 value
            const float nf = (float)n;
            c0 = (f00 * nf < NYQ) ? c0 : 0.0f; // anti-alias masks (ref semantics)
            c1 = (f01 * nf < NYQ) ? c1 : 0.0f;
            const float cup = w1 * c0 + w * c1;

            double ph = fma((double)nf, Phi, (double)rpn);
            double fr = ph - floor(ph);                    // fractional revs
            acc = fmaf(cup * vup04, __builtin_amdgcn_sinf((float)fr), acc);
        }
    }

    __shared__ float part[4][64];
    part[wave][k] = acc;
    __syncthreads();
    if (tid < 64) {
        float sum = part[0][tid] + part[1][tid] + part[2][tid] + part[3][tid];
        out[(size_t)b * AUDIO + t * UP + tid] = sum;
    }
}

extern "C" void kernel_launch(void* const* d_in, const int* in_sizes, int n_in,
                              void* d_out, int out_size, void* d_ws, size_t ws_size,
                              hipStream_t stream) {
    const float* f0 = (const float*)d_in[0];   // (2,8,500)
    const float* c  = (const float*)d_in[1];   // (2,8,64,500)
    const float* v  = (const float*)d_in[2];   // (2,8,500)
    // d_in[3] = a (loudness) — unused by the output
    const float* rp = (const float*)d_in[4];   // (2,512,1)
    float* out = (float*)d_out;                // (2,32000)

    double* P = (double*)d_ws;                 // 16*500*8 = 64 KB

    k_prefix<<<2 * POLY, 64, 0, stream>>>(f0, P);
    k_main<<<2 * FRAMES, 256, 0, stream>>>(f0, c, v, rp, P, out);
}

// Round 3
// 25.022 us; speedup vs baseline: 1.6244x; 1.6244x over previous
//
#include <hip/hip_runtime.h>
#include <math.h>

#define SR_I 16000
#define FRAMES 500
#define UP 64
#define AUDIO (FRAMES * UP)
#define POLY 8
#define HARM 64
#define NYQ 8000.0f

// largest n with (float)n * f < NYQ under exact f32 semantics
__device__ __forceinline__ int nyq_limit(float f) {
    int m = (int)(NYQ / f);
    while ((float)(m + 1) * f < NYQ) ++m;
    while (m > 0 && (float)m * f >= NYQ) --m;
    return m;
}

// -------------------------------------------------------------------------
// Kernel 1: per (b,p) row, exclusive f64 prefix of per-frame sums of
// upsample(f0)/SR.  Frame-sum closed form (scale=64, align_corners=False):
//   interior t:  8*x[t-1] + 48*x[t] + 8*x[t+1]
//   t=0: 56*x[0]+8*x[1];  t=499: 8*x[498]+56*x[499]
// -------------------------------------------------------------------------
__global__ __launch_bounds__(64) void k_prefix(const float* __restrict__ f0,
                                               double* __restrict__ P) {
    const int bp = blockIdx.x;      // 0..15
    const int lane = threadIdx.x;   // 0..63
    const float* x = f0 + bp * FRAMES;
    double* Pp = P + bp * FRAMES;

    double carry = 0.0;
    for (int ch = 0; ch < 8; ++ch) {
        int t = ch * 64 + lane;
        double F = 0.0;
        if (t < FRAMES) {
            double xm = (double)x[t > 0 ? t - 1 : 0];
            double xc = (double)x[t];
            double xp = (double)x[t < FRAMES - 1 ? t + 1 : FRAMES - 1];
            double wa = 8.0, wb = 48.0, wc = 8.0;
            if (t == 0)          { wa = 0.0; wb = 56.0; wc = 8.0; }
            if (t == FRAMES - 1) { wa = 8.0; wb = 56.0; wc = 0.0; }
            F = (wa * xm + wb * xc + wc * xp) * (1.0 / (double)SR_I);
        }
        double s = F;
        #pragma unroll
        for (int off = 1; off < 64; off <<= 1) {
            double o = __shfl_up(s, off, 64);
            if (lane >= off) s += o;
        }
        if (t < FRAMES) Pp[t] = carry + (s - F);   // exclusive prefix
        carry += __shfl(s, 63, 64);
    }
}

// -------------------------------------------------------------------------
// Kernel 2: one block per (b, frame t); 8 waves; wave p = voice p.
// Lane k owns output sample j = t*64 + k.
// Per-voice LDS quads[half][n] = {c[n,i0], c[n,i1], rp[n], 0} so the inner
// harmonic loop is ONE ds_read_b128 (2-way broadcast) + f32 math + v_sin.
// -------------------------------------------------------------------------
__global__ __launch_bounds__(512) void k_main(const float* __restrict__ f0,
                                              const float* __restrict__ cc,
                                              const float* __restrict__ vv,
                                              const float* __restrict__ rp,
                                              const double* __restrict__ P,
                                              float* __restrict__ out) {
    __shared__ float4 quads[POLY][2][HARM];   // 16 KiB
    __shared__ float part[POLY][UP];          // 2 KiB

    const int blk = blockIdx.x;           // 0 .. 2*FRAMES-1
    const int b = blk / FRAMES;
    const int t = blk - b * FRAMES;
    const int tid = threadIdx.x;
    const int p = tid >> 6;               // wave index = voice
    const int k = tid & 63;

    // linear-interp coords for sample j = t*64 + k (exact in f32)
    float srcf = (float)t + ((float)k - 31.5f) * (1.0f / 64.0f);
    srcf = fmaxf(srcf, 0.0f);
    const int i0 = (int)srcf;
    const int i1 = min(i0 + 1, FRAMES - 1);
    const float w = srcf - (float)i0;
    const float w1 = 1.0f - w;

    const int tm = max(t - 1, 0);
    const int tp = min(t + 1, FRAMES - 1);

    const int bpi = b * POLY + p;
    const float* f0p = f0 + bpi * FRAMES;
    const float* vp  = vv + bpi * FRAMES;
    const float* cp  = cc + (size_t)bpi * HARM * FRAMES;

    // stage per-voice quads: lane k holds harmonic k
    const float chm = cp[k * FRAMES + tm];
    const float chc = cp[k * FRAMES + t];
    const float chp = cp[k * FRAMES + tp];
    const float rpl = rp[bpi * HARM + k];
    quads[p][0][k] = make_float4(chm, chc, rpl, 0.0f);   // lanes 0..31: (i0,i1)=(tm?,t)
    quads[p][1][k] = make_float4(chc, chp, rpl, 0.0f);   // lanes 32..63: (t, tp)

    const float f00 = f0p[i0];
    const float f01 = f0p[i1];
    const float vup04 = 0.04f * (w1 * vp[i0] + w * vp[i1]);
    const float W0 = w1 * vup04;
    const float W1 = w * vup04;

    // exact per-lane anti-alias limits (mask n<=N passes)
    const int N0 = nyq_limit(f00);
    const int N1 = nyq_limit(f01);

    // f64 phase: exclusive frame prefix + in-frame 64-lane scan
    double s = ((double)w1 * (double)f00 + (double)w * (double)f01)
               * (1.0 / (double)SR_I);
    #pragma unroll
    for (int off = 1; off < 64; off <<= 1) {
        double o = __shfl_up(s, off, 64);
        if (k >= off) s += o;
    }
    const double Phi = P[bpi * FRAMES + t] + s;
    const float phi = (float)(Phi - floor(Phi));   // exact frac, then f32

    // wave-uniform harmonic cap, rounded up to 4 (extras are masked to zero)
    int nmax = max(N0, N1);
    #pragma unroll
    for (int off = 32; off; off >>= 1)
        nmax = max(nmax, __shfl_xor(nmax, off, 64));
    int hmax = min(nmax, HARM);
    hmax = (hmax + 3) & ~3;

    const float4* qb = &quads[p][k < 32 ? 0 : 1][0];

    float acc0 = 0.0f, acc1 = 0.0f, acc2 = 0.0f, acc3 = 0.0f;
    float nf0 = 1.0f, nf1 = 2.0f, nf2 = 3.0f, nf3 = 4.0f;

    for (int n0 = 1; n0 <= hmax; n0 += 4) {
        const float4 qa = qb[n0 - 1];
        const float4 qc = qb[n0 + 0];
        const float4 qd = qb[n0 + 1];
        const float4 qe = qb[n0 + 2];

        {
            float c0 = (n0 <= N0) ? qa.x : 0.0f;
            float c1 = (n0 <= N1) ? qa.y : 0.0f;
            float cup = fmaf(W1, c1, W0 * c0);
            float ph = fmaf(nf0, phi, qa.z);
            acc0 = fmaf(cup, __builtin_amdgcn_sinf(__builtin_amdgcn_fractf(ph)), acc0);
        }
        {
            float c0 = (n0 + 1 <= N0) ? qc.x : 0.0f;
            float c1 = (n0 + 1 <= N1) ? qc.y : 0.0f;
            float cup = fmaf(W1, c1, W0 * c0);
            float ph = fmaf(nf1, phi, qc.z);
            acc1 = fmaf(cup, __builtin_amdgcn_sinf(__builtin_amdgcn_fractf(ph)), acc1);
        }
        {
            float c0 = (n0 + 2 <= N0) ? qd.x : 0.0f;
            float c1 = (n0 + 2 <= N1) ? qd.y : 0.0f;
            float cup = fmaf(W1, c1, W0 * c0);
            float ph = fmaf(nf2, phi, qd.z);
            acc2 = fmaf(cup, __builtin_amdgcn_sinf(__builtin_amdgcn_fractf(ph)), acc2);
        }
        {
            float c0 = (n0 + 3 <= N0) ? qe.x : 0.0f;
            float c1 = (n0 + 3 <= N1) ? qe.y : 0.0f;
            float cup = fmaf(W1, c1, W0 * c0);
            float ph = fmaf(nf3, phi, qe.z);
            acc3 = fmaf(cup, __builtin_amdgcn_sinf(__builtin_amdgcn_fractf(ph)), acc3);
        }
        nf0 += 4.0f; nf1 += 4.0f; nf2 += 4.0f; nf3 += 4.0f;
    }

    part[p][k] = (acc0 + acc1) + (acc2 + acc3);
    __syncthreads();
    if (tid < 64) {
        float sum = 0.0f;
        #pragma unroll
        for (int q = 0; q < POLY; ++q) sum += part[q][tid];
        out[(size_t)b * AUDIO + t * UP + tid] = sum;
    }
}

extern "C" void kernel_launch(void* const* d_in, const int* in_sizes, int n_in,
                              void* d_out, int out_size, void* d_ws, size_t ws_size,
                              hipStream_t stream) {
    const float* f0 = (const float*)d_in[0];   // (2,8,500)
    const float* c  = (const float*)d_in[1];   // (2,8,64,500)
    const float* v  = (const float*)d_in[2];   // (2,8,500)
    // d_in[3] = a (loudness) — unused by the output
    const float* rp = (const float*)d_in[4];   // (2,512,1)
    float* out = (float*)d_out;                // (2,32000)

    double* P = (double*)d_ws;                 // 16*500*8 = 64 KB

    k_prefix<<<2 * POLY, 64, 0, stream>>>(f0, P);
    k_main<<<2 * FRAMES, 512, 0, stream>>>(f0, c, v, rp, P, out);
}